// Round 8
// baseline (84.757 us; speedup 1.0000x reference)
//
#include <hip/hip_runtime.h>

typedef unsigned int u32;
typedef __fp16 h2v __attribute__((ext_vector_type(2)));
typedef __fp16 h4 __attribute__((ext_vector_type(4)));
typedef float f32x16 __attribute__((ext_vector_type(16)));

#define NB 256
#define NNODE 256
#define FF 128
#define DD 8
#define HDIM 32

__device__ __forceinline__ h2v bch2(u32 u) { return __builtin_bit_cast(h2v, u); }
__device__ __forceinline__ h4 bch4(uint2 u) { return __builtin_bit_cast(h4, u); }
__device__ __forceinline__ u32 bcu(h2v v) { return __builtin_bit_cast(u32, v); }
__device__ __forceinline__ f32x16 fzero() {
  f32x16 z;
  #pragma unroll
  for (int r = 0; r < 16; ++r) z[r] = 0.f;
  return z;
}
__device__ __forceinline__ f32x16 mfma8(h4 a, h4 b, f32x16 c) {
  return __builtin_amdgcn_mfma_f32_32x32x8f16(a, b, c, 0, 0, 0);
}

// -------- prep_w: zero mask; WtH[c][kp] f16-packed W^T cols; bias f32 ----------
__global__ __launch_bounds__(256) void prep_w_kernel(
    const float* __restrict__ Wq, const float* __restrict__ bq,
    const float* __restrict__ Wk, const float* __restrict__ bk,
    const float* __restrict__ Wv, const float* __restrict__ bv,
    u32* __restrict__ mask, u32* __restrict__ WtH, float* __restrict__ bias)
{
  int g = blockIdx.x * 256 + threadIdx.x;
  if (g < 96 * 64) {                      // WtH[c][kp]: pack W[2kp][c],W[2kp+1][c]
    int c = g >> 6, f = (g & 63) * 2;
    const float* W = (c < 32) ? Wq : ((c < 64) ? Wk : Wv);
    int cc = c & 31;
    h2v p = __builtin_amdgcn_cvt_pkrtz(W[f*HDIM + cc], W[(f+1)*HDIM + cc]);
    WtH[g] = bcu(p);
  }
  if (g < NNODE * 8) mask[g] = 0u;
  if (g < 96) {
    const float* bb = (g < 32) ? bq : ((g < 64) ? bk : bv);
    bias[g] = bb[g & 31];
  }
}

__global__ __launch_bounds__(256) void prep_e_kernel(
    const int* __restrict__ eidx, int E, u32* __restrict__ mask)
{
  int e = blockIdx.x * 256 + threadIdx.x;
  if (e < E) {
    int r = eidx[e], c = eidx[E + e];
    atomicOr(&mask[r*8 + (c >> 5)], 1u << (c & 31));
  }
}

// -------- per-(batch,head) fused kernel helpers --------------------------------
__device__ __forceinline__ void qkv_tile(
    const float* __restrict__ xr, const u32* wLds, int l31, int hi, int h,
    float bk_, float bv_, f32x16& aq, __fp16* kS, __fp16* vt, int ti)
{
  f32x16 ak, av;
  #pragma unroll
  for (int r = 0; r < 16; ++r) { ak[r] = bk_; av[r] = bv_; }
  #pragma unroll
  for (int ks = 0; ks < 16; ++ks) {
    float4 xf = *(const float4*)(xr + ks * 8);
    h2v xl = __builtin_amdgcn_cvt_pkrtz(xf.x, xf.y);
    h2v xh = __builtin_amdgcn_cvt_pkrtz(xf.z, xf.w);
    h4 xfrag = __builtin_shufflevector(xl, xh, 0, 1, 2, 3);
    h4 wk = bch4(*(const uint2*)&wLds[l31*66 + ks*4 + 2*hi]);
    h4 wv = bch4(*(const uint2*)&wLds[(32 + l31)*66 + ks*4 + 2*hi]);
    h4 wq = bch4(*(const uint2*)&wLds[(64 + (l31 & 7))*66 + ks*4 + 2*hi]);
    ak = mfma8(xfrag, wk, ak);        // k: lane=hd-col, reg=node-row
    av = mfma8(xfrag, wv, av);        // v: same
    aq = mfma8(wq, xfrag, aq);        // q^T (head slice): lane=node, regs0-3=d
  }
  if ((l31 >> 3) == h) {              // only this head's 8 hd-columns are kept
    int d = l31 & 7;
    #pragma unroll
    for (int r = 0; r < 16; ++r) {
      int node = ti*32 + (r & 3) + 8*(r >> 2) + 4*hi;
      kS[node*12 + d] = (__fp16)ak[r];
      vt[d*260 + node] = (__fp16)av[r];
    }
  }
}

__device__ __forceinline__ void epilogue(
    const f32x16& acc, float lp, int qnode, int b, int h, int hi,
    const float* woS, const float* boS, float* __restrict__ out)
{
  float lq = lp + __shfl_xor(lp, 32);
  float inv = 1.0f / lq;
  float o[4];
  #pragma unroll
  for (int j = 0; j < 4; ++j) o[j] = acc[j] * inv;   // d_local = 4*hi + j
  float pa[8];
  #pragma unroll
  for (int dd = 0; dd < 8; ++dd) {
    float s = 0.f;
    #pragma unroll
    for (int j = 0; j < 4; ++j)
      s = __builtin_fmaf(o[j], woS[(8*h + 4*hi + j)*8 + dd], s);
    s += __shfl_xor(s, 32);           // combine the two d-halves -> full head sum
    if (h == 0) s += boS[dd];
    pa[dd] = s;
  }
  float* op = out + ((size_t)b * NNODE + qnode) * DD;
  #pragma unroll
  for (int d2 = 0; d2 < 4; ++d2)
    unsafeAtomicAdd(op + 4*hi + d2, pa[4*hi + d2]);
}

// -------- fused: block = (b, h); 4 waves; qkv -> attn -> proj-partial ----------
__global__ __launch_bounds__(256, 4) void fused_kernel(
    const float* __restrict__ x, const u32* __restrict__ WtH,
    const float* __restrict__ bias, const u32* __restrict__ mask,
    const float* __restrict__ Wo, const float* __restrict__ bo,
    float* __restrict__ out)
{
  __shared__ u32 wLds[72 * 66];        // rows 0-31 Wk, 32-63 Wv, 64-71 Wq[head]
  __shared__ __fp16 kS[NNODE * 12];    // k head-slice [node][8d], stride 12
  __shared__ __fp16 vt[8 * 260];       // V^T head-slice [8d][256node], stride 260
  __shared__ float woS[256];
  __shared__ float boS[8];

  int t = threadIdx.x, lane = t & 63, w = t >> 6;   // 4 waves
  int l31 = lane & 31, hi = lane >> 5;
  int bid = blockIdx.x;
  int b = bid & 255, h = bid >> 8;     // h-major: same-b blocks 256 apart -> same XCD

  for (int g = t; g < 72 * 64; g += 256) {
    int dr = g >> 6, c = g & 63;
    int sr = (dr < 64) ? (32 + dr) : (8*h + dr - 64);
    wLds[dr * 66 + c] = WtH[sr * 64 + c];
  }
  woS[t & 255] = Wo[t & 255];
  if (t < 8) boS[t] = bo[t];

  float bk_ = bias[32 + l31], bv_ = bias[64 + l31];
  f32x16 aq0, aq1;
  #pragma unroll
  for (int r = 0; r < 16; ++r) {
    float bq_ = (r < 4) ? bias[8*h + 4*hi + r] : 0.f;
    aq0[r] = bq_; aq1[r] = bq_;
  }
  __syncthreads();

  // ---- QKV: wave handles node tiles 2w, 2w+1 (also its q-rows) ----
  const float* xb = x + (size_t)b * NNODE * FF + 4 * hi;
  qkv_tile(xb + (size_t)((2*w    )*32 + l31) * FF, wLds, l31, hi, h,
           bk_, bv_, aq0, kS, vt, 2*w);
  qkv_tile(xb + (size_t)((2*w + 1)*32 + l31) * FF, wLds, l31, hi, h,
           bk_, bv_, aq1, kS, vt, 2*w + 1);

  // Q B-frags from aq regs 0..3 (d_local = 4hi+j); masks for own q-rows
  h2v qa0 = __builtin_amdgcn_cvt_pkrtz(aq0[0], aq0[1]);
  h2v qb0 = __builtin_amdgcn_cvt_pkrtz(aq0[2], aq0[3]);
  h4 Qf0 = __builtin_shufflevector(qa0, qb0, 0, 1, 2, 3);
  h2v qa1 = __builtin_amdgcn_cvt_pkrtz(aq1[0], aq1[1]);
  h2v qb1 = __builtin_amdgcn_cvt_pkrtz(aq1[2], aq1[3]);
  h4 Qf1 = __builtin_shufflevector(qa1, qb1, 0, 1, 2, 3);

  int qn0 = (2*w)*32 + l31, qn1 = qn0 + 32;
  uint4 ma0 = *(const uint4*)(mask + qn0*8);
  uint4 ma1 = *(const uint4*)(mask + qn0*8 + 4);
  uint4 mb0 = *(const uint4*)(mask + qn1*8);
  uint4 mb1 = *(const uint4*)(mask + qn1*8 + 4);
  u32 mwA[8] = { ma0.x, ma0.y, ma0.z, ma0.w, ma1.x, ma1.y, ma1.z, ma1.w };
  u32 mwB[8] = { mb0.x, mb0.y, mb0.z, mb0.w, mb1.x, mb1.y, mb1.z, mb1.w };
  #pragma unroll
  for (int i = 0; i < 8; ++i) {       // bit index = (r&3) + 8*(r>>2) + 4*hi
    if (hi) { mwA[i] >>= 4; mwB[i] >>= 4; }
  }
  __syncthreads();

  // ---- attention: 2 q-tile chains, 1 head ----
  const float sc2 = 0.51006977f;       // (1/sqrt(8)) * log2(e)
  f32x16 accO0 = fzero(), accO1 = fzero();
  float lp0 = 0.f, lp1 = 0.f;
  #pragma unroll
  for (int kt = 0; kt < 8; ++kt) {
    h4 Kf = bch4(*(const uint2*)&kS[(kt*32 + l31)*12 + 4*hi]);
    f32x16 T0 = mfma8(Kf, Qf0, fzero());   // T[kr][q=l31]
    f32x16 T1 = mfma8(Kf, Qf1, fzero());
    u32 m0 = mwA[kt], m1 = mwB[kt];
    #pragma unroll
    for (int kk = 0; kk < 4; ++kk) {
      float p0[4], p1[4];
      #pragma unroll
      for (int j = 0; j < 4; ++j) {
        int r = 4*kk + j, bp = 8*kk + j;
        float e0 = __builtin_fmaf(T0[r], sc2, -8.0f);  // anchor 2^-8, f16-safe
        float e1 = __builtin_fmaf(T1[r], sc2, -8.0f);
        p0[j] = ((m0 >> bp) & 1u) ? __builtin_amdgcn_exp2f(e0) : 0.f;
        p1[j] = ((m1 >> bp) & 1u) ? __builtin_amdgcn_exp2f(e1) : 0.f;
        lp0 += p0[j]; lp1 += p1[j];
      }
      u32 pw0a = bcu(__builtin_amdgcn_cvt_pkrtz(p0[0], p0[1]));
      u32 pw0b = bcu(__builtin_amdgcn_cvt_pkrtz(p0[2], p0[3]));
      u32 pw1a = bcu(__builtin_amdgcn_cvt_pkrtz(p1[0], p1[1]));
      u32 pw1b = bcu(__builtin_amdgcn_cvt_pkrtz(p1[2], p1[3]));
      h4 va = bch4(*(const uint2*)&vt[(l31 & 7)*260 + kt*32 + kk*8 + 4*hi]);
      accO0 = mfma8(va, bch4(make_uint2(pw0a, pw0b)), accO0);
      accO1 = mfma8(va, bch4(make_uint2(pw1a, pw1b)), accO1);
    }
  }

  // ---- epilogue: normalize, per-head partial proj, atomic accumulate ----
  epilogue(accO0, lp0, qn0, b, h, hi, woS, boS, out);
  epilogue(accO1, lp1, qn1, b, h, hi, woS, boS, out);
}

extern "C" void kernel_launch(void* const* d_in, const int* in_sizes, int n_in,
                              void* d_out, int out_size, void* d_ws, size_t ws_size,
                              hipStream_t stream)
{
  const float* x  = (const float*)d_in[0];
  const int*   ei = (const int*)d_in[1];
  const float* Wq = (const float*)d_in[2];
  const float* bq = (const float*)d_in[3];
  const float* Wk = (const float*)d_in[4];
  const float* bk = (const float*)d_in[5];
  const float* Wv = (const float*)d_in[6];
  const float* bv = (const float*)d_in[7];
  const float* Wo = (const float*)d_in[8];
  const float* bo = (const float*)d_in[9];
  int E = in_sizes[1] / 2;

  char* ws = (char*)d_ws;
  u32*   mask = (u32*)(ws + 0);                 // 8 KB
  u32*   WtH  = (u32*)(ws + 8192);              // 24 KB: W^T[c][kp] f16-packed
  float* bias = (float*)(ws + 32768);           // 384 B

  hipMemsetAsync(d_out, 0, (size_t)out_size * sizeof(float), stream);
  prep_w_kernel<<<24, 256, 0, stream>>>(Wq, bq, Wk, bk, Wv, bv, mask, WtH, bias);
  prep_e_kernel<<<(E + 255) / 256, 256, 0, stream>>>(ei, E, mask);
  fused_kernel<<<NB * 4, 256, 0, stream>>>(x, WtH, bias, mask, Wo, bo,
                                           (float*)d_out);
}

// Round 9
// 45.985 us; speedup vs baseline: 1.8431x; 1.8431x over previous
//
#include <hip/hip_runtime.h>

typedef unsigned int u32;
typedef __fp16 h2v __attribute__((ext_vector_type(2)));
typedef __fp16 h4 __attribute__((ext_vector_type(4)));
typedef float f32x16 __attribute__((ext_vector_type(16)));

#define NB 256
#define NNODE 256
#define FF 128
#define DD 8
#define HDIM 32

__device__ __forceinline__ float dot2(h2v a, h2v b, float c) {
  return __builtin_amdgcn_fdot2(a, b, c, false);
}
__device__ __forceinline__ h2v bch2(u32 u) { return __builtin_bit_cast(h2v, u); }
__device__ __forceinline__ h4 bch4(uint2 u) { return __builtin_bit_cast(h4, u); }
__device__ __forceinline__ u32 bcu(h2v v) { return __builtin_bit_cast(u32, v); }
__device__ __forceinline__ f32x16 fzero() {
  f32x16 z;
  #pragma unroll
  for (int r = 0; r < 16; ++r) z[r] = 0.f;
  return z;
}
__device__ __forceinline__ f32x16 mfma8(h4 a, h4 b, f32x16 c) {
  return __builtin_amdgcn_mfma_f32_32x32x8f16(a, b, c, 0, 0, 0);
}

// -------- prep_w: zero mask; WtH[c][kp] f16-packed W^T; bias f32; WoT packed ----
__global__ __launch_bounds__(256) void prep_w_kernel(
    const float* __restrict__ Wq, const float* __restrict__ bq,
    const float* __restrict__ Wk, const float* __restrict__ bk,
    const float* __restrict__ Wv, const float* __restrict__ bv,
    const float* __restrict__ Wo,
    u32* __restrict__ mask, u32* __restrict__ WtH, float* __restrict__ bias,
    u32* __restrict__ woT2)
{
  int g = blockIdx.x * 256 + threadIdx.x;
  if (g < 96 * 64) {                      // WtH[c][kp]: pack W[2kp][c],W[2kp+1][c]
    int c = g >> 6, f = (g & 63) * 2;
    const float* W = (c < 32) ? Wq : ((c < 64) ? Wk : Wv);
    int cc = c & 31;
    WtH[g] = bcu(__builtin_amdgcn_cvt_pkrtz(W[f*HDIM + cc], W[(f+1)*HDIM + cc]));
  }
  if (g < NNODE * 8) mask[g] = 0u;
  if (g < 96) {
    const float* bb = (g < 32) ? bq : ((g < 64) ? bk : bv);
    bias[g] = bb[g & 31];
  }
  if (g < 128) {                          // woT2[d][p] = pack Wo[2p][d],Wo[2p+1][d]
    int d = g >> 4, p = g & 15;
    woT2[g] = bcu(__builtin_amdgcn_cvt_pkrtz(Wo[(2*p)*DD + d], Wo[(2*p+1)*DD + d]));
  }
}

__global__ __launch_bounds__(256) void prep_e_kernel(
    const int* __restrict__ eidx, int E, u32* __restrict__ mask)
{
  int e = blockIdx.x * 256 + threadIdx.x;
  if (e < E) {
    int r = eidx[e], c = eidx[E + e];
    atomicOr(&mask[r*8 + (c >> 5)], 1u << (c & 31));
  }
}

// -------- fused: 2 blocks/batch, 8 waves; wave = 1 qkv tile, (qt,hp) attn ------
__global__ __launch_bounds__(512, 4) void fused_kernel(
    const float* __restrict__ x, const u32* __restrict__ WtH,
    const float* __restrict__ bias, const u32* __restrict__ mask,
    const u32* __restrict__ woT2, const float* __restrict__ bo,
    float* __restrict__ out)
{
  __shared__ u32 wLds[96 * 66];        // 25.3 KB: rows 0-31 Wq, 32-63 Wk, 64-95 Wv
  __shared__ __fp16 kS[NNODE * 36];    // 18 KB: K all heads, stride 36
  __shared__ __fp16 vt32[32 * 260];    // 16.6 KB: V^T all heads, stride 260
  __shared__ __fp16 qS[128 * 36];      // 9 KB: own-half q rows (as [node][hd])
  __shared__ __fp16 oS[128 * 36];      // 9 KB: attn out rows
  __shared__ u32 woSu[128];
  __shared__ float boS[8];

  int t = threadIdx.x, lane = t & 63, w = t >> 6;   // 8 waves
  int l31 = lane & 31, hi = lane >> 5;
  int b = blockIdx.x >> 1, half = blockIdx.x & 1;

  // stage W (coalesced global, strided LDS)
  for (int g = t; g < 96 * 64; g += 512)
    wLds[(g >> 6) * 66 + (g & 63)] = WtH[g];
  if (t < 128) woSu[t] = woT2[t];
  if (t < 8) boS[t] = bo[t];

  // masks for this wave's attn q-rows (load early, overlaps QKV)
  int qt = w >> 1, hp = w & 1;
  int qnode = half*128 + qt*32 + l31;
  uint4 m0 = *(const uint4*)(mask + qnode*8);
  uint4 m1 = *(const uint4*)(mask + qnode*8 + 4);
  u32 mw8[8] = { m0.x, m0.y, m0.z, m0.w, m1.x, m1.y, m1.z, m1.w };
  #pragma unroll
  for (int i = 0; i < 8; ++i) mw8[i] = hi ? (mw8[i] >> 4) : mw8[i];

  // ---- QKV: wave w computes k,v for node tile w; q^T too if tile in own half
  int tile = w;
  bool own = (w >> 2) == half;
  int qtl = w & 3;                     // local q-tile if own
  float bk_ = bias[32 + l31], bv_ = bias[64 + l31];
  f32x16 ak, av, aq;
  #pragma unroll
  for (int r = 0; r < 16; ++r) {
    ak[r] = bk_; av[r] = bv_;
    aq[r] = bias[(r & 3) + 8*(r >> 2) + 4*hi];
  }
  __syncthreads();                     // wLds ready

  const float* xr = x + ((size_t)b * NNODE + tile*32 + l31) * FF + 4 * hi;
  #pragma unroll
  for (int ks = 0; ks < 16; ++ks) {
    float4 xf = *(const float4*)(xr + ks * 8);
    h2v xl = __builtin_amdgcn_cvt_pkrtz(xf.x, xf.y);
    h2v xh = __builtin_amdgcn_cvt_pkrtz(xf.z, xf.w);
    h4 xfrag = __builtin_shufflevector(xl, xh, 0, 1, 2, 3);
    h4 wk = bch4(*(const uint2*)&wLds[(32 + l31)*66 + ks*4 + 2*hi]);
    h4 wv = bch4(*(const uint2*)&wLds[(64 + l31)*66 + ks*4 + 2*hi]);
    ak = mfma8(xfrag, wk, ak);         // k: lane=hd-col, regs=node-rows
    av = mfma8(xfrag, wv, av);
    if (own) {
      h4 wq = bch4(*(const uint2*)&wLds[l31*66 + ks*4 + 2*hi]);
      aq = mfma8(wq, xfrag, aq);       // q^T: lane=node-col, regs=hd-rows
    }
  }
  #pragma unroll
  for (int r = 0; r < 16; ++r) {
    int rc = (r & 3) + 8*(r >> 2) + 4*hi;   // node-row (k,v) or hd-row (q)
    int node = tile*32 + rc;
    kS[node * 36 + l31] = (__fp16)ak[r];
    vt32[l31 * 260 + node] = (__fp16)av[r];
    if (own) qS[(qtl*32 + l31) * 36 + rc] = (__fp16)aq[r];
  }
  __syncthreads();

  // ---- attention: wave = (qt, head pair hp); 2 chains ----
  int h0 = 2*hp, h1 = 2*hp + 1;
  h4 Qf0 = bch4(*(const uint2*)&qS[(qt*32 + l31)*36 + 8*h0 + 4*hi]);
  h4 Qf1 = bch4(*(const uint2*)&qS[(qt*32 + l31)*36 + 8*h1 + 4*hi]);

  const float sc2 = 0.51006977f;       // (1/sqrt(8)) * log2(e)
  f32x16 accO0 = fzero(), accO1 = fzero();
  float lp0 = 0.f, lp1 = 0.f;
  #pragma unroll
  for (int kt = 0; kt < 8; ++kt) {
    h4 Kf0 = bch4(*(const uint2*)&kS[(kt*32 + l31)*36 + 8*h0 + 4*hi]);
    h4 Kf1 = bch4(*(const uint2*)&kS[(kt*32 + l31)*36 + 8*h1 + 4*hi]);
    f32x16 T0 = mfma8(Kf0, Qf0, fzero());   // T[kr][q=l31]
    f32x16 T1 = mfma8(Kf1, Qf1, fzero());
    u32 mwh = mw8[kt];
    #pragma unroll
    for (int kk = 0; kk < 4; ++kk) {
      float p0[4], p1[4];
      #pragma unroll
      for (int j = 0; j < 4; ++j) {
        int r = 4*kk + j, bp = 8*kk + j;
        bool mbit = (mwh >> bp) & 1u;
        float e0 = __builtin_fmaf(T0[r], sc2, -8.0f);  // anchor 2^-8, f16-safe
        float e1 = __builtin_fmaf(T1[r], sc2, -8.0f);
        p0[j] = mbit ? __builtin_amdgcn_exp2f(e0) : 0.f;
        p1[j] = mbit ? __builtin_amdgcn_exp2f(e1) : 0.f;
        lp0 += p0[j]; lp1 += p1[j];
      }
      u32 pw0a = bcu(__builtin_amdgcn_cvt_pkrtz(p0[0], p0[1]));
      u32 pw0b = bcu(__builtin_amdgcn_cvt_pkrtz(p0[2], p0[3]));
      u32 pw1a = bcu(__builtin_amdgcn_cvt_pkrtz(p1[0], p1[1]));
      u32 pw1b = bcu(__builtin_amdgcn_cvt_pkrtz(p1[2], p1[3]));
      h4 va = bch4(*(const uint2*)&vt32[l31*260 + kt*32 + kk*8 + 4*hi]);
      accO0 = mfma8(va, bch4(make_uint2(pw0a, pw0b)), accO0);
      accO1 = mfma8(va, bch4(make_uint2(pw1a, pw1b)), accO1);
    }
  }
  {
    float lq0 = lp0 + __shfl_xor(lp0, 32);
    float lq1 = lp1 + __shfl_xor(lp1, 32);
    float inv0 = 1.0f / lq0, inv1 = 1.0f / lq1;
    h2v a0 = __builtin_amdgcn_cvt_pkrtz(accO0[4*h0]*inv0,   accO0[4*h0+1]*inv0);
    h2v a1 = __builtin_amdgcn_cvt_pkrtz(accO0[4*h0+2]*inv0, accO0[4*h0+3]*inv0);
    *(uint2*)&oS[(qt*32 + l31)*36 + 8*h0 + 4*hi] = make_uint2(bcu(a0), bcu(a1));
    h2v c0 = __builtin_amdgcn_cvt_pkrtz(accO1[4*h1]*inv1,   accO1[4*h1+1]*inv1);
    h2v c1 = __builtin_amdgcn_cvt_pkrtz(accO1[4*h1+2]*inv1, accO1[4*h1+3]*inv1);
    *(uint2*)&oS[(qt*32 + l31)*36 + 8*h1 + 4*hi] = make_uint2(bcu(c0), bcu(c1));
  }
  __syncthreads();

  // ---- proj: 512 thr, 128 rows; thread = (row, d-pair) ----
  int row = t >> 2, d0 = (t & 3) * 2;
  float r2[2] = { boS[d0], boS[d0 + 1] };
  #pragma unroll
  for (int p = 0; p < 16; ++p) {
    h2v o2 = bch2(*(const u32*)&oS[row*36 + 2*p]);
    r2[0] = dot2(o2, bch2(woSu[(d0    )*16 + p]), r2[0]);
    r2[1] = dot2(o2, bch2(woSu[(d0 + 1)*16 + p]), r2[1]);
  }
  float2 o = { r2[0], r2[1] };
  *(float2*)(out + ((size_t)b * NNODE + half*128 + row) * DD + d0) = o;
}

extern "C" void kernel_launch(void* const* d_in, const int* in_sizes, int n_in,
                              void* d_out, int out_size, void* d_ws, size_t ws_size,
                              hipStream_t stream)
{
  const float* x  = (const float*)d_in[0];
  const int*   ei = (const int*)d_in[1];
  const float* Wq = (const float*)d_in[2];
  const float* bq = (const float*)d_in[3];
  const float* Wk = (const float*)d_in[4];
  const float* bk = (const float*)d_in[5];
  const float* Wv = (const float*)d_in[6];
  const float* bv = (const float*)d_in[7];
  const float* Wo = (const float*)d_in[8];
  const float* bo = (const float*)d_in[9];
  int E = in_sizes[1] / 2;

  char* ws = (char*)d_ws;
  u32*   mask = (u32*)(ws + 0);                 // 8 KB
  u32*   WtH  = (u32*)(ws + 8192);              // 24 KB: W^T[c][kp] f16-packed
  float* bias = (float*)(ws + 32768);           // 384 B
  u32*   woT2 = (u32*)(ws + 33280);             // 512 B

  prep_w_kernel<<<24, 256, 0, stream>>>(Wq, bq, Wk, bk, Wv, bv, Wo,
                                        mask, WtH, bias, woT2);
  prep_e_kernel<<<(E + 255) / 256, 256, 0, stream>>>(ei, E, mask);
  fused_kernel<<<NB * 2, 512, 0, stream>>>(x, WtH, bias, mask, woT2, bo,
                                           (float*)d_out);
}